// Round 11
// baseline (496.501 us; speedup 1.0000x reference)
//
#include <hip/hip_runtime.h>
#include <math.h>

// z: (B=16, C=512, H=64, W=64) f32 ; codebook: (K=2048, D=64)
// tokens N = B*H*W = 65536

// ---------------- prep kernels ----------------

// wiT[c][d] = g[d] * v[d][c] / ||v[d,:]||
__global__ void k_prep_wi(const float* __restrict__ v, const float* __restrict__ g,
                          float* __restrict__ wiT){
  const int d = blockIdx.x;          // 64
  const int tid = threadIdx.x;       // 256
  float s = 0.f;
  for (int c = tid; c < 512; c += 256){ float x = v[d*512+c]; s = fmaf(x,x,s); }
  __shared__ float red[4];
  #pragma unroll
  for (int o = 32; o > 0; o >>= 1) s += __shfl_down(s, o);
  if ((tid & 63) == 0) red[tid >> 6] = s;
  __syncthreads();
  const float nrm = sqrtf(red[0]+red[1]+red[2]+red[3]);
  const float gd = g[d];
  for (int c = tid; c < 512; c += 256) wiT[c*64 + d] = gd * v[d*512+c] / nrm;
}

__global__ void k_prep_wo(const float* __restrict__ v, const float* __restrict__ g,
                          float* __restrict__ wot){
  const int c = blockIdx.x;          // 512
  const int d = threadIdx.x;         // 64
  const float x = v[c*64+d];
  float s = x*x;
  #pragma unroll
  for (int o = 32; o > 0; o >>= 1) s += __shfl_down(s, o);
  const float nrm = __shfl(sqrtf(s), 0);
  wot[d*512 + c] = g[c] * x / nrm;   // WoT[d][c]
}

// Table[k][c] = sum_d cb[k][d]*WoT[d][c] + ob[c];  ne[k] = ||cb[k]||^2;
// cbm2T[d][k] = -2*cb[k][d]
__global__ void k_table(const float* __restrict__ cbk, const float* __restrict__ wot,
                        const float* __restrict__ ob, float* __restrict__ table,
                        float* __restrict__ ne, float* __restrict__ cbm2T){
  const int k = blockIdx.x;          // 2048
  const int tid = threadIdx.x;       // 512
  __shared__ float e[64];
  if (tid < 64) e[tid] = cbk[k*64 + tid];
  __syncthreads();
  if (tid < 64){
    float x = e[tid];
    cbm2T[tid*2048 + k] = -2.0f * x;
    float s = x*x;
    #pragma unroll
    for (int o = 32; o > 0; o >>= 1) s += __shfl_down(s, o);
    if (tid == 0) ne[k] = s;
  }
  const int c = tid;
  float acc = ob[c];
  #pragma unroll 16
  for (int d = 0; d < 64; d++) acc = fmaf(e[d], wot[d*512 + c], acc);
  table[(size_t)k*512 + c] = acc;
}

// ---------------- phase 1: in_proj -> z_e to global [d][t] (r3-proven) -------
__global__ __launch_bounds__(256, 1) void k_inproj(
    const float* __restrict__ z, const float* __restrict__ wiT,
    const float* __restrict__ inb, float* __restrict__ ze)
{
  __shared__ __align__(16) float z_s[16*256];   // [c][t]
  __shared__ __align__(16) float wi_s[16*68];   // [c][d]
  const int tid = threadIdx.x;
  const int T0  = blockIdx.x << 8;
  const int b   = T0 >> 12;
  const int hw0 = T0 & 4095;
  const float* zb = z + ((size_t)b << 21) + hw0;

  const int tgp = tid & 31;
  const int dgp = tid >> 5;
  const int ccb = tid >> 6;
  const int c64 = tid & 63;

  float acc[8][8];
  #pragma unroll
  for (int i = 0; i < 8; i++)
    #pragma unroll
    for (int j = 0; j < 8; j++) acc[i][j] = 0.f;

  float4 pz[4]; float pw[4];
  #pragma unroll
  for (int q = 0; q < 4; q++){
    pz[q] = *(const float4*)(zb + (size_t)(ccb + 4*q) * 4096 + c64*4);
    pw[q] = wiT[(ccb + 4*q)*64 + c64];
  }
  #pragma unroll
  for (int q = 0; q < 4; q++){
    *(float4*)&z_s[(ccb + 4*q)*256 + c64*4] = pz[q];
    wi_s[(ccb + 4*q)*68 + c64] = pw[q];
  }
  __syncthreads();

  for (int c0 = 0;;){
    const int nxt = c0 + 16;
    if (nxt < 512){
      #pragma unroll
      for (int q = 0; q < 4; q++){
        pz[q] = *(const float4*)(zb + (size_t)(nxt + ccb + 4*q) * 4096 + c64*4);
        pw[q] = wiT[(nxt + ccb + 4*q)*64 + c64];
      }
    }
    #pragma unroll 4
    for (int cc = 0; cc < 16; cc++){
      const float4 ta = *(const float4*)&z_s[cc*256 + tgp*4];
      const float4 tb = *(const float4*)&z_s[cc*256 + 128 + tgp*4];
      const float4 w0 = *(const float4*)&wi_s[cc*68 + dgp*8];
      const float4 w1 = *(const float4*)&wi_s[cc*68 + dgp*8 + 4];
      const float tv[8] = {ta.x,ta.y,ta.z,ta.w, tb.x,tb.y,tb.z,tb.w};
      const float wv[8] = {w0.x,w0.y,w0.z,w0.w, w1.x,w1.y,w1.z,w1.w};
      #pragma unroll
      for (int i = 0; i < 8; i++)
        #pragma unroll
        for (int j = 0; j < 8; j++)
          acc[i][j] = fmaf(tv[j], wv[i], acc[i][j]);
    }
    if (nxt >= 512) break;
    __syncthreads();
    #pragma unroll
    for (int q = 0; q < 4; q++){
      *(float4*)&z_s[(ccb + 4*q)*256 + c64*4] = pz[q];
      wi_s[(ccb + 4*q)*68 + c64] = pw[q];
    }
    __syncthreads();
    c0 = nxt;
  }

  #pragma unroll
  for (int i = 0; i < 8; i++){
    const int d = dgp*8 + i;
    const float bd = inb[d];
    float4 o0 = {acc[i][0]+bd, acc[i][1]+bd, acc[i][2]+bd, acc[i][3]+bd};
    float4 o1 = {acc[i][4]+bd, acc[i][5]+bd, acc[i][6]+bd, acc[i][7]+bd};
    *(float4*)(ze + (size_t)d*65536 + T0 + tgp*4)       = o0;
    *(float4*)(ze + (size_t)d*65536 + T0 + 128 + tgp*4) = o1;
  }
}

// ---------------- phase 2: barrier-free quarter-codebook scan ----------------
// Block = 64 tokens x 512 codes (quarter q). LDS: cb quarter [32kg][1044]
// (pad 1044 -> kg*1044%32 hits 8 disjoint bank-quads: conflict-free) +
// ze [64][68]. 151 KB -> 1 block/CU, 4 waves. Single d-loop, ZERO barriers.
// Thread tile 8t x 16k (F=128 FMA, L=6 b128: best LDS ratio).
__global__ __launch_bounds__(256, 1) void k_scan(
    const float* __restrict__ zebuf, const float* __restrict__ cbm2T,
    const float* __restrict__ ne, float* __restrict__ candv,
    int* __restrict__ candi)
{
  __shared__ __align__(16) float cb_s[32*1044];   // 133632 B
  __shared__ __align__(16) float ze_s[64*68];     // 17408 B
  const int tid = threadIdx.x;
  const int q  = blockIdx.x & 3;
  const int t0 = (blockIdx.x >> 2) << 6;

  // stage cb quarter: cb_s[kg][d][j] = -2cb[q*512+kg*16+j][d]
  {
    const float* src = cbm2T + (q << 9);
    for (int m = 0; m < 32; m++){
      const int g = m*1024 + tid*4;
      const int d = g >> 9, kcol = g & 511;
      const float4 v = *(const float4*)(src + d*2048 + kcol);
      *(float4*)&cb_s[(kcol >> 4)*1044 + d*16 + (kcol & 15)] = v;
    }
  }
  // stage ze tile [64][68]
  {
    const int r0 = tid >> 4, c4 = (tid & 15) << 2;
    #pragma unroll
    for (int m = 0; m < 4; m++){
      const int d = r0 + m*16;
      *(float4*)&ze_s[d*68 + c4] =
          *(const float4*)(zebuf + (size_t)d*65536 + t0 + c4);
    }
  }
  __syncthreads();

  const int tg = tid & 7;            // tokens tg*8..+7
  const int kg = tid >> 3;           // codes kg*16..+15 within quarter
  const int kbase = (q << 9) + (kg << 4);

  float acc[8][16];
  #pragma unroll
  for (int i4 = 0; i4 < 4; i4++){
    const float4 nv = *(const float4*)&ne[kbase + i4*4];
    #pragma unroll
    for (int j = 0; j < 8; j++){
      acc[j][i4*4  ] = nv.x; acc[j][i4*4+1] = nv.y;
      acc[j][i4*4+2] = nv.z; acc[j][i4*4+3] = nv.w;
    }
  }

#define P8(CV, I) \
  acc[0][I]=fmaf(za.x ,CV,acc[0][I]); acc[1][I]=fmaf(za.y ,CV,acc[1][I]); \
  acc[2][I]=fmaf(za.z ,CV,acc[2][I]); acc[3][I]=fmaf(za.w ,CV,acc[3][I]); \
  acc[4][I]=fmaf(zb4.x,CV,acc[4][I]); acc[5][I]=fmaf(zb4.y,CV,acc[5][I]); \
  acc[6][I]=fmaf(zb4.z,CV,acc[6][I]); acc[7][I]=fmaf(zb4.w,CV,acc[7][I]);

  const float* cbr = &cb_s[kg*1044];
  #pragma unroll 2
  for (int d = 0; d < 64; d++){
    const float4 za  = *(const float4*)&ze_s[d*68 + tg*8];
    const float4 zb4 = *(const float4*)&ze_s[d*68 + tg*8 + 4];
    const float4 c0 = *(const float4*)(cbr + d*16);
    const float4 c1 = *(const float4*)(cbr + d*16 + 4);
    const float4 c2 = *(const float4*)(cbr + d*16 + 8);
    const float4 c3 = *(const float4*)(cbr + d*16 + 12);
    P8(c0.x, 0)  P8(c0.y, 1)  P8(c0.z, 2)  P8(c0.w, 3)
    P8(c1.x, 4)  P8(c1.y, 5)  P8(c1.z, 6)  P8(c1.w, 7)
    P8(c2.x, 8)  P8(c2.y, 9)  P8(c2.z,10)  P8(c2.w,11)
    P8(c3.x,12)  P8(c3.y,13)  P8(c3.z,14)  P8(c3.w,15)
  }
#undef P8

  float best[8]; int bidx[8];
  #pragma unroll
  for (int j = 0; j < 8; j++){ best[j] = INFINITY; bidx[j] = 0; }
  #pragma unroll
  for (int i = 0; i < 16; i++){
    const int k = kbase + i;
    #pragma unroll
    for (int j = 0; j < 8; j++)
      if (acc[j][i] < best[j]){ best[j] = acc[j][i]; bidx[j] = k; }
  }

  // in-block kg-reduce (overlay cb_s; all reads of cb_s complete after barrier)
  __syncthreads();
  float* rb = cb_s;                  // [64 tok][32 kg]
  int*   ri = (int*)(cb_s + 2048);
  #pragma unroll
  for (int j = 0; j < 8; j++){
    const int t = tg*8 + j;
    rb[t*32 + kg] = best[j];
    ri[t*32 + kg] = bidx[j];
  }
  __syncthreads();

  if (tid < 64){
    const int t = tid;
    float bv = rb[t*32]; int bi = ri[t*32];
    #pragma unroll
    for (int kk = 1; kk < 32; kk++){
      const float vq = rb[t*32 + kk]; const int iq = ri[t*32 + kk];
      if (vq < bv || (vq == bv && iq < bi)){ bv = vq; bi = iq; }
    }
    candv[(q << 16) + t0 + t] = bv;
    candi[(q << 16) + t0 + t] = bi;
  }
}

// ---------------- merge + loss + gather ----------------
__global__ __launch_bounds__(256) void k_merge(
    const float* __restrict__ candv, const int* __restrict__ candi,
    const float* __restrict__ zebuf, const float* __restrict__ cbk,
    const float* __restrict__ table, float* __restrict__ out,
    float* __restrict__ oidx, double* __restrict__ loss)
{
  __shared__ int bidx_s[64];
  const int tid = threadIdx.x;
  const int t0  = blockIdx.x << 6;
  const int b   = t0 >> 12;
  const int hw0 = t0 & 4095;

  if (tid < 64){
    const int t = tid;
    float bv = candv[t0 + t]; int bi = candi[t0 + t];
    #pragma unroll
    for (int qq = 1; qq < 4; qq++){
      const float vq = candv[(qq << 16) + t0 + t];
      const int   iq = candi[(qq << 16) + t0 + t];
      if (vq < bv){ bv = vq; bi = iq; }    // q asc = k asc; strict < keeps lower k
    }
    bidx_s[t] = bi;
    oidx[t0 + t] = (float)bi;
    float myloss = 0.f;
    const float* e = cbk + (size_t)bi * 64;
    #pragma unroll 8
    for (int d = 0; d < 64; d++){
      const float diff = zebuf[(size_t)d*65536 + t0 + t] - e[d];
      myloss = fmaf(diff, diff, myloss);
    }
    #pragma unroll
    for (int o = 32; o > 0; o >>= 1) myloss += __shfl_down(myloss, o);
    if (t == 0) atomicAdd(loss, (double)myloss);
  }
  __syncthreads();

  // output gather: out[b][c][hw] = Table[idx][c]
  {
    const int tl = tid & 63, cg = tid >> 6;       // 4 c-groups x 128 c
    const int myk = bidx_s[tl];
    const float* trow = table + ((size_t)myk << 9) + cg*128;
    float* ob = out + (((size_t)b) << 21) + hw0 + tl;
    #pragma unroll 4
    for (int ci = 0; ci < 32; ci++){
      const float4 v = *(const float4*)(trow + ci*4);
      const size_t cbase = (size_t)(cg*128 + ci*4) << 12;
      ob[cbase        ] = v.x;
      ob[cbase +  4096] = v.y;
      ob[cbase +  8192] = v.z;
      ob[cbase + 12288] = v.w;
    }
  }
}

__global__ void k_finish(const double* __restrict__ loss, float* __restrict__ oloss){
  *oloss = (float)(1.25 * (*loss) / 4194304.0);   // 1.25 * mean over B*D*H*W
}

// ---------------- launch ----------------

extern "C" void kernel_launch(void* const* d_in, const int* in_sizes, int n_in,
                              void* d_out, int out_size, void* d_ws, size_t ws_size,
                              hipStream_t stream) {
  const float* z   = (const float*)d_in[0];
  const float* cbk = (const float*)d_in[1];
  const float* inv = (const float*)d_in[2];
  const float* ing = (const float*)d_in[3];
  const float* inb = (const float*)d_in[4];
  const float* ov  = (const float*)d_in[5];
  const float* og  = (const float*)d_in[6];
  const float* ob  = (const float*)d_in[7];

  float* ws    = (float*)d_ws;
  float* wiT   = ws;                       // [512][64]
  float* wot   = ws + 32768;               // [64][512]
  float* table = ws + 65536;               // [2048][512]
  float* ne    = ws + 1114112;             // [2048]
  double* loss = (double*)(ws + 1116160);  // 8B aligned
  float* cbm2T = ws + 1179648;             // [64][2048] = 512 KB
  float* zebuf = ws + 2097152;             // [64][65536] = 16 MB
  float* candv = ws + 6291456;             // [4][65536]
  int*   candi = (int*)(ws + 6553600);     // [4][65536]

  float* out   = (float*)d_out;            // [16][512][4096]
  float* oidx  = out + 33554432;           // [65536]
  float* oloss = out + 33619968;           // scalar

  hipMemsetAsync(loss, 0, sizeof(double), stream);
  k_prep_wi<<<64, 256, 0, stream>>>(inv, ing, wiT);
  k_prep_wo<<<512, 64, 0, stream>>>(ov, og, wot);
  k_table<<<2048, 512, 0, stream>>>(cbk, wot, ob, table, ne, cbm2T);
  k_inproj<<<256, 256, 0, stream>>>(z, wiT, inb, zebuf);
  k_scan<<<4096, 256, 0, stream>>>(zebuf, cbm2T, ne, candv, candi);
  k_merge<<<1024, 256, 0, stream>>>(candv, candi, zebuf, cbk, table, out, oidx, loss);
  k_finish<<<1, 1, 0, stream>>>(loss, oloss);
}

// Round 12
// 325.985 us; speedup vs baseline: 1.5231x; 1.5231x over previous
//
#include <hip/hip_runtime.h>
#include <math.h>

// z: (B=16, C=512, H=64, W=64) f32 ; codebook: (K=2048, D=64)
// tokens N = B*H*W = 65536; fused kernel: 64 tokens/block, grid 1024.

typedef __attribute__((address_space(1))) const unsigned int* gas_ptr;
typedef __attribute__((address_space(3))) unsigned int* las_ptr;
#define GLD_LDS16(gsrc, ldst) \
  __builtin_amdgcn_global_load_lds((gas_ptr)(const void*)(gsrc), \
                                   (las_ptr)(void*)(ldst), 16, 0, 0)

// ---------------- prep kernels ----------------

// wiT[c][d] = g[d] * v[d][c] / ||v[d,:]||
__global__ void k_prep_wi(const float* __restrict__ v, const float* __restrict__ g,
                          float* __restrict__ wiT){
  const int d = blockIdx.x;          // 64
  const int tid = threadIdx.x;       // 256
  float s = 0.f;
  for (int c = tid; c < 512; c += 256){ float x = v[d*512+c]; s = fmaf(x,x,s); }
  __shared__ float red[4];
  #pragma unroll
  for (int o = 32; o > 0; o >>= 1) s += __shfl_down(s, o);
  if ((tid & 63) == 0) red[tid >> 6] = s;
  __syncthreads();
  const float nrm = sqrtf(red[0]+red[1]+red[2]+red[3]);
  const float gd = g[d];
  for (int c = tid; c < 512; c += 256) wiT[c*64 + d] = gd * v[d*512+c] / nrm;
}

__global__ void k_prep_wo(const float* __restrict__ v, const float* __restrict__ g,
                          float* __restrict__ wot){
  const int c = blockIdx.x;          // 512
  const int d = threadIdx.x;         // 64
  const float x = v[c*64+d];
  float s = x*x;
  #pragma unroll
  for (int o = 32; o > 0; o >>= 1) s += __shfl_down(s, o);
  const float nrm = __shfl(sqrtf(s), 0);
  wot[d*512 + c] = g[c] * x / nrm;   // WoT[d][c]
}

// Table[k][c] = sum_d cb[k][d]*WoT[d][c] + ob[c];  ne[k] = ||cb[k]||^2;
// cbm2T[d][k] = -2*cb[k][d]  (prescaled, transposed; -2*x exact in fp32)
__global__ void k_table(const float* __restrict__ cbk, const float* __restrict__ wot,
                        const float* __restrict__ ob, float* __restrict__ table,
                        float* __restrict__ ne, float* __restrict__ cbm2T){
  const int k = blockIdx.x;          // 2048
  const int tid = threadIdx.x;       // 512
  __shared__ float e[64];
  if (tid < 64) e[tid] = cbk[k*64 + tid];
  __syncthreads();
  if (tid < 64){
    float x = e[tid];
    cbm2T[tid*2048 + k] = -2.0f * x;
    float s = x*x;
    #pragma unroll
    for (int o = 32; o > 0; o >>= 1) s += __shfl_down(s, o);
    if (tid == 0) ne[k] = s;
  }
  const int c = tid;
  float acc = ob[c];
  #pragma unroll 16
  for (int d = 0; d < 64; d++) acc = fmaf(e[d], wot[d*512 + c], acc);
  table[(size_t)k*512 + c] = acc;
}

// ---------------- fused main: in_proj + distances + argmin + loss + gather ----
// 64 tokens/block, grid 1024 (4 blocks/CU; LDS 35KB, VGPR 84 @ (256,2)).
// r7 structure verbatim + T5 s_setprio wrapped around the pure-FMA bursts
// (DMA-staged 64-stage pipeline = phase-split schedule -> T5 regime applies).
__global__ __launch_bounds__(256, 2) void k_main(
    const float* __restrict__ z, const float* __restrict__ wiT,
    const float* __restrict__ inb, const float* __restrict__ cbm2T,
    const float* __restrict__ cbk, const float* __restrict__ ne,
    const float* __restrict__ table, float* __restrict__ out,
    float* __restrict__ oidx, double* __restrict__ loss)
{
  __shared__ __align__(16) float ze_s[64*68];     // 17408 B [d][t], pad 68
  __shared__ __align__(16) float rgb[2*2176];     // 17408 B union: {z,wi} / cb dbuf
  __shared__ int bidx_s[64];

  const int tid  = threadIdx.x;
  const int w    = tid >> 6;         // wave 0..3
  const int lane = tid & 63;
  const int t0   = blockIdx.x << 6;  // 64 tokens
  const int b    = t0 >> 12;
  const int hw0  = t0 & 4095;
  const float* zb = z + ((size_t)b << 21) + hw0;

  const int tg  = tid & 15;          // token group: tokens tg*4..+3
  const int dgp = tid >> 4;          // phase1: d = dgp*4..+3 ; phase2: kg = codes

  // ---------------- phase 1 ----------------
  const int srow = w*4 + (lane >> 4);      // 0..15
  const int scol = (lane & 15) << 2;       // 0..60

  float acc1[4][4];
  #pragma unroll
  for (int i = 0; i < 4; i++)
    #pragma unroll
    for (int j = 0; j < 4; j++) acc1[i][j] = 0.f;

  // prologue: chunk 0 -> buf 0
  GLD_LDS16(zb + (size_t)srow*4096 + scol,  &rgb[0*2176 + w*256]);
  GLD_LDS16(wiT + srow*64 + scol,           &rgb[0*2176 + 1024 + w*256]);
  __syncthreads();

  for (int c = 0; c < 32; c++){
    const int buf = c & 1;
    if (c < 31){
      const int c0n = (c+1) << 4;
      GLD_LDS16(zb + (size_t)(c0n + srow)*4096 + scol, &rgb[(buf^1)*2176 + w*256]);
      GLD_LDS16(wiT + (c0n + srow)*64 + scol,          &rgb[(buf^1)*2176 + 1024 + w*256]);
    }
    const float* zc = &rgb[buf*2176];
    const float* wc = &rgb[buf*2176 + 1024];
    __builtin_amdgcn_s_setprio(1);
    #pragma unroll 4
    for (int cc = 0; cc < 16; cc++){
      const float4 ta = *(const float4*)&zc[cc*64 + tg*4];
      const float4 wv = *(const float4*)&wc[cc*64 + dgp*4];
      // acc1[d][t] += ta[t] * wv[d]
      acc1[0][0]=fmaf(ta.x,wv.x,acc1[0][0]); acc1[0][1]=fmaf(ta.y,wv.x,acc1[0][1]);
      acc1[0][2]=fmaf(ta.z,wv.x,acc1[0][2]); acc1[0][3]=fmaf(ta.w,wv.x,acc1[0][3]);
      acc1[1][0]=fmaf(ta.x,wv.y,acc1[1][0]); acc1[1][1]=fmaf(ta.y,wv.y,acc1[1][1]);
      acc1[1][2]=fmaf(ta.z,wv.y,acc1[1][2]); acc1[1][3]=fmaf(ta.w,wv.y,acc1[1][3]);
      acc1[2][0]=fmaf(ta.x,wv.z,acc1[2][0]); acc1[2][1]=fmaf(ta.y,wv.z,acc1[2][1]);
      acc1[2][2]=fmaf(ta.z,wv.z,acc1[2][2]); acc1[2][3]=fmaf(ta.w,wv.z,acc1[2][3]);
      acc1[3][0]=fmaf(ta.x,wv.w,acc1[3][0]); acc1[3][1]=fmaf(ta.y,wv.w,acc1[3][1]);
      acc1[3][2]=fmaf(ta.z,wv.w,acc1[3][2]); acc1[3][3]=fmaf(ta.w,wv.w,acc1[3][3]);
    }
    __builtin_amdgcn_s_setprio(0);
    __syncthreads();                 // drains next-chunk DMA; gates buf reuse
  }

  // epilogue: + in_b -> ze_s[d][t]
  #pragma unroll
  for (int i = 0; i < 4; i++){
    const int d = dgp*4 + i;
    const float bd = inb[d];
    float4 o = {acc1[i][0]+bd, acc1[i][1]+bd, acc1[i][2]+bd, acc1[i][3]+bd};
    *(float4*)&ze_s[d*68 + tg*4] = o;
  }
  __syncthreads();                   // ze_s ready; rgb free for cb

  // ---------------- phase 2 ----------------
  const int kg = dgp;                // codes kg*16..+15 within 256-chunk
  float best[4]; int bidx[4];
  #pragma unroll
  for (int j = 0; j < 4; j++){ best[j] = INFINITY; bidx[j] = 0; }

  // prologue: DMA stage 0 into buf 0 (rows 2w, 2w+1 of 8)
  {
    const float* gbs = cbm2T + (size_t)(2*w)*2048 + lane*4;
    GLD_LDS16(gbs,        &rgb[0*2176 + (2*w)  *272]);
    GLD_LDS16(gbs + 2048, &rgb[0*2176 + (2*w+1)*272]);
  }
  __syncthreads();

  // acc[t][k]: t = za component, k = c0..c3 component
#define P2(CV, I) \
  acc[0][I]=fmaf(za.x,CV,acc[0][I]); acc[1][I]=fmaf(za.y,CV,acc[1][I]); \
  acc[2][I]=fmaf(za.z,CV,acc[2][I]); acc[3][I]=fmaf(za.w,CV,acc[3][I]);

  float acc[4][16];
  for (int s = 0; s < 64; s++){
    const int buf = s & 1;
    const int dq = s & 7, kc = (s >> 3) << 8;
    if (s < 63){
      const int s1 = s + 1;
      const int ndq = s1 & 7, nkc = (s1 >> 3) << 8;
      const float* gbs = cbm2T + (size_t)(ndq*8 + 2*w)*2048 + nkc + lane*4;
      GLD_LDS16(gbs,        &rgb[(buf^1)*2176 + (2*w)  *272]);
      GLD_LDS16(gbs + 2048, &rgb[(buf^1)*2176 + (2*w+1)*272]);
    }
    if (dq == 0){                    // acc init from ||e||^2 (order-preserving)
      #pragma unroll
      for (int q = 0; q < 4; q++){
        const float4 nv = *(const float4*)&ne[kc + kg*16 + q*4];
        acc[0][q*4  ]=nv.x; acc[1][q*4  ]=nv.x; acc[2][q*4  ]=nv.x; acc[3][q*4  ]=nv.x;
        acc[0][q*4+1]=nv.y; acc[1][q*4+1]=nv.y; acc[2][q*4+1]=nv.y; acc[3][q*4+1]=nv.y;
        acc[0][q*4+2]=nv.z; acc[1][q*4+2]=nv.z; acc[2][q*4+2]=nv.z; acc[3][q*4+2]=nv.z;
        acc[0][q*4+3]=nv.w; acc[1][q*4+3]=nv.w; acc[2][q*4+3]=nv.w; acc[3][q*4+3]=nv.w;
      }
    }
    const float* cbf = &rgb[buf*2176];
    const int dbase = dq << 3;
    __builtin_amdgcn_s_setprio(1);
    #pragma unroll
    for (int d = 0; d < 8; d++){
      const int dr = dbase + d;
      const float4 za = *(const float4*)&ze_s[dr*68 + tg*4];
      const float4 c0 = *(const float4*)&cbf[d*272 + kg*16];
      const float4 c1 = *(const float4*)&cbf[d*272 + kg*16 + 4];
      const float4 c2 = *(const float4*)&cbf[d*272 + kg*16 + 8];
      const float4 c3 = *(const float4*)&cbf[d*272 + kg*16 + 12];
      P2(c0.x, 0)  P2(c0.y, 1)  P2(c0.z, 2)  P2(c0.w, 3)
      P2(c1.x, 4)  P2(c1.y, 5)  P2(c1.z, 6)  P2(c1.w, 7)
      P2(c2.x, 8)  P2(c2.y, 9)  P2(c2.z,10)  P2(c2.w,11)
      P2(c3.x,12)  P2(c3.y,13)  P2(c3.z,14)  P2(c3.w,15)
    }
    __builtin_amdgcn_s_setprio(0);
    if (dq == 7){
      #pragma unroll
      for (int i = 0; i < 16; i++){
        const int k = kc + kg*16 + i;
        #pragma unroll
        for (int j = 0; j < 4; j++)
          if (acc[j][i] < best[j]){ best[j] = acc[j][i]; bidx[j] = k; }
      }
    }
    __syncthreads();                 // drains next-stage DMA; gates buf reuse
  }
#undef P2

  // cross-thread argmin reduce (16 threads per token), overlay on rgb
  float* rb = rgb;                   // [64][16]
  int*   ri = (int*)(rgb + 1024);    // [64][16]
  #pragma unroll
  for (int j = 0; j < 4; j++){
    const int t = tg*4 + j;
    rb[t*16 + kg] = best[j];
    ri[t*16 + kg] = bidx[j];
  }
  __syncthreads();

  if (tid < 64){
    const int t = tid;
    float bv = rb[t*16]; int bi = ri[t*16];
    #pragma unroll
    for (int q = 1; q < 16; q++){
      const float vq = rb[t*16 + q]; const int iq = ri[t*16 + q];
      if (vq < bv || (vq == bv && iq < bi)){ bv = vq; bi = iq; }
    }
    bidx_s[t] = bi;
    oidx[t0 + t] = (float)bi;
    // loss: sum_d (z_e - e)^2 for this token
    float myloss = 0.f;
    const float* e = cbk + (size_t)bi * 64;
    #pragma unroll 8
    for (int d = 0; d < 64; d++){
      const float diff = ze_s[d*68 + t] - e[d];
      myloss = fmaf(diff, diff, myloss);
    }
    #pragma unroll
    for (int o = 32; o > 0; o >>= 1) myloss += __shfl_down(myloss, o);
    if (t == 0) atomicAdd(loss, (double)myloss);
  }
  __syncthreads();

  // output gather: out[b][c][hw] = Table[idx][c]
  {
    const int tl = tid & 63, cg = tid >> 6;       // 4 c-groups x 128 c
    const int myk = bidx_s[tl];
    const float* trow = table + ((size_t)myk << 9) + cg*128;
    float* ob = out + (((size_t)b) << 21) + hw0 + tl;
    #pragma unroll 4
    for (int ci = 0; ci < 32; ci++){
      const float4 v = *(const float4*)(trow + ci*4);
      const size_t cbase = (size_t)(cg*128 + ci*4) << 12;
      ob[cbase        ] = v.x;
      ob[cbase +  4096] = v.y;
      ob[cbase +  8192] = v.z;
      ob[cbase + 12288] = v.w;
    }
  }
}

__global__ void k_finish(const double* __restrict__ loss, float* __restrict__ oloss){
  *oloss = (float)(1.25 * (*loss) / 4194304.0);   // 1.25 * mean over B*D*H*W
}

// ---------------- launch ----------------

extern "C" void kernel_launch(void* const* d_in, const int* in_sizes, int n_in,
                              void* d_out, int out_size, void* d_ws, size_t ws_size,
                              hipStream_t stream) {
  const float* z   = (const float*)d_in[0];
  const float* cbk = (const float*)d_in[1];
  const float* inv = (const float*)d_in[2];
  const float* ing = (const float*)d_in[3];
  const float* inb = (const float*)d_in[4];
  const float* ov  = (const float*)d_in[5];
  const float* og  = (const float*)d_in[6];
  const float* ob  = (const float*)d_in[7];

  float* ws    = (float*)d_ws;
  float* wiT   = ws;                       // [512][64]
  float* wot   = ws + 32768;               // [64][512]
  float* table = ws + 65536;               // [2048][512]
  float* ne    = ws + 65536 + 1048576;     // [2048]
  double* loss = (double*)(ws + 1116160);  // 8B aligned
  float* cbm2T = ws + 1179648;             // [64][2048] = 512 KB

  float* out   = (float*)d_out;            // [16][512][4096]
  float* oidx  = out + 33554432;           // [65536]
  float* oloss = out + 33619968;           // scalar

  hipMemsetAsync(loss, 0, sizeof(double), stream);
  k_prep_wi<<<64, 256, 0, stream>>>(inv, ing, wiT);
  k_prep_wo<<<512, 64, 0, stream>>>(ov, og, wot);
  k_table<<<2048, 512, 0, stream>>>(cbk, wot, ob, table, ne, cbm2T);
  k_main<<<1024, 256, 0, stream>>>(z, wiT, inb, cbm2T, cbk, ne, table, out, oidx, loss);
  k_finish<<<1, 1, 0, stream>>>(loss, oloss);
}